// Round 7
// baseline (321.655 us; speedup 1.0000x reference)
//
#include <hip/hip_runtime.h>

typedef float f32x4  __attribute__((ext_vector_type(4)));
typedef float f32x16 __attribute__((ext_vector_type(16)));
typedef short s16x8  __attribute__((ext_vector_type(8)));

constexpr int NL  = 31;
constexpr int BB  = 64;
constexpr int TT  = 512;
constexpr int DD  = 768;
constexpr int RTOT = BB * TT;
constexpr int IDX_EOS = 29;
constexpr int IDX_BOS = 30;
constexpr float LOG2E = 1.4426950408889634f;
constexpr float LN2F  = 0.6931471805599453f;

union Frag8 { unsigned u[4]; s16x8 s; };

__device__ inline unsigned pk2(float a, float b) {
  unsigned ua = __float_as_uint(a), ub = __float_as_uint(b);
  ua = (ua + 0x7fffu + ((ua >> 16) & 1u)) >> 16;   // RNE f32->bf16
  ub = (ub + 0x7fffu + ((ub >> 16) & 1u)) >> 16;
  return ua | (ub << 16);
}
__device__ inline unsigned short bf16r(float a) {
  unsigned ua = __float_as_uint(a);
  return (unsigned short)((ua + 0x7fffu + ((ua >> 16) & 1u)) >> 16);
}

__device__ inline float bfly_max32(float v) {
#define STEPM(K) { float o = __int_as_float(__builtin_amdgcn_ds_swizzle(__float_as_int(v), ((K) << 10) | 0x1f)); v = fmaxf(v, o); }
  STEPM(1) STEPM(2) STEPM(4) STEPM(8) STEPM(16)
#undef STEPM
  return v;
}
__device__ inline float bfly_sum32(float v) {
#define STEPS(K) { float o = __int_as_float(__builtin_amdgcn_ds_swizzle(__float_as_int(v), ((K) << 10) | 0x1f)); v = v + o; }
  STEPS(1) STEPS(2) STEPS(4) STEPS(8) STEPS(16)
#undef STEPS
  return v;
}

// D(C-layout, f32[16]) -> B-frag(bf16) half-swap repack [R2-verified]
__device__ inline void repack(const float E[16], int h, Frag8& B1, Frag8& B2) {
  unsigned o1a = pk2(E[4 * h], E[4 * h + 1]), o1b = pk2(E[4 * h + 2], E[4 * h + 3]);
  unsigned o2a = pk2(E[8 + 4 * h], E[8 + 4 * h + 1]), o2b = pk2(E[8 + 4 * h + 2], E[8 + 4 * h + 3]);
  int hb = 4 * (1 - h);
  unsigned s1a = pk2(E[hb], E[hb + 1]),         s1b = pk2(E[hb + 2], E[hb + 3]);
  unsigned s2a = pk2(E[8 + hb], E[8 + hb + 1]), s2b = pk2(E[8 + hb + 2], E[8 + hb + 3]);
  unsigned r1a = __shfl_xor((int)s1a, 32), r1b = __shfl_xor((int)s1b, 32);
  unsigned r2a = __shfl_xor((int)s2a, 32), r2b = __shfl_xor((int)s2b, 32);
  if (h == 0) {
    B1.u[0] = o1a; B1.u[1] = o1b; B1.u[2] = r1a; B1.u[3] = r1b;
    B2.u[0] = o2a; B2.u[1] = o2b; B2.u[2] = r2a; B2.u[3] = r2b;
  } else {
    B1.u[0] = r1a; B1.u[1] = r1b; B1.u[2] = o1a; B1.u[3] = o1b;
    B2.u[0] = r2a; B2.u[1] = r2b; B2.u[2] = o2a; B2.u[3] = o2b;
  }
}

__device__ inline void renorm16(float E[16], float& Sacc) {
  float m = E[0];
#pragma unroll
  for (int r = 1; r < 16; ++r) m = fmaxf(m, E[r]);
  m = bfly_max32(m);
  m = fmaxf(m, __shfl_xor(m, 32));
  float lg = truncf(log2f(m));
  Sacc += lg;
  float sc = exp2f(-lg);
#pragma unroll
  for (int r = 0; r < 16; ++r) E[r] *= sc;
}

// bf16 row-major 32x32 matrix -> A-frags (A[m][k], m = lane&31)
__device__ inline void load_A16(const unsigned short* M, int l, int h, Frag8& A1, Frag8& A2) {
  A1.s = *(const s16x8*)(M + l * 32 + 8 * h);
  A2.s = *(const s16x8*)(M + l * 32 + 16 + 8 * h);
}
// bf16 row-major 32x32 matrix -> B-frags (B[k][n], n = lane&31)
__device__ inline void load_B16(const unsigned short* M, int l, int h, Frag8& B1, Frag8& B2) {
#pragma unroll
  for (int m = 0; m < 4; ++m) {
    int k = 8 * h + 2 * m;
    unsigned lo0 = M[k * 32 + l],        hi0 = M[(k + 1) * 32 + l];
    unsigned lo1 = M[(k + 16) * 32 + l], hi1 = M[(k + 17) * 32 + l];
    B1.u[m] = lo0 | (hi0 << 16);
    B2.u[m] = lo1 | (hi1 << 16);
  }
}

// LDS tree node: result = T[ja] * T[jb] -> stored at T[jb] (bf16), Ts[jb] += S
// (ja = LATER segment, jb = EARLIER segment)  [R2-verified]
__device__ inline void tree_node(unsigned short* Tb, float* Ts, int ja, int jb, int l, int h) {
  Frag8 A1, A2, B1, B2;
  load_A16(Tb + ja * 1024, l, h, A1, A2);
  load_B16(Tb + jb * 1024, l, h, B1, B2);
  f32x16 D = {};
  D = __builtin_amdgcn_mfma_f32_32x32x16_bf16(A1.s, B1.s, D, 0, 0, 0);
  D = __builtin_amdgcn_mfma_f32_32x32x16_bf16(A2.s, B2.s, D, 0, 0, 0);
  float E[16];
#pragma unroll
  for (int r = 0; r < 16; ++r) E[r] = D[r];
  float S = Ts[ja] + Ts[jb];
  renorm16(E, S);
#pragma unroll
  for (int r = 0; r < 16; ++r) {
    int row = (r & 3) + 8 * (r >> 2) + 4 * h;
    Tb[jb * 1024 + row * 32 + l] = bf16r(E[r]);
  }
  if (l == 0 && h == 0) Ts[jb] = S;
}

// ------------- K0: state_w -> bf16 padded ----------------------------------
__global__ void k_prep(const float* __restrict__ sw, unsigned short* __restrict__ Bw) {
  for (int i = blockIdx.x * 256 + threadIdx.x; i < 32 * DD; i += 8 * 256)
    Bw[i] = (i < NL * DD) ? bf16r(sw[i]) : (unsigned short)0;
}

// ------------- K_A: GEMM + outs + tgt partial + seg chain (NO energy) -------
// 2048 blocks x 16 rows, 8 blocks/CU.
//  ph1: 4-way K-split GEMM (wave w -> K-chunks 3w..3w+2) -> accbuf
//  ph3: all-thread reduce + epilogue -> osh + global outs
//  ph5: 4-step seg sub-product per wave -> Ms/Ss (trans read from global, L2-hot)
//  ph7: wave0 = 3-product combine -> Mb/Sb; wave1 = tgt partial
__global__ __launch_bounds__(256, 8) void k_A(
    const float* __restrict__ inp, const unsigned short* __restrict__ Bw,
    const float* __restrict__ sb, const float* __restrict__ msk,
    const float* __restrict__ trans, const int* __restrict__ target,
    float* __restrict__ outs, float* __restrict__ ws_partial,
    unsigned short* __restrict__ Mb, float* __restrict__ Sb,
    float* __restrict__ out0)
{
  __shared__ __align__(16) union {
    float accbuf[4][16][33];     // ph1-ph3 (8448 B)
    float ubw[4][128];           // ph5     (2048 B)
  } ovl;
  __shared__ __align__(16) float osh[16 * 32];
  __shared__ __align__(16) unsigned short Ms[4][1024];
  __shared__ float Ss[4];

  int tid = threadIdx.x, wave = tid >> 6, lane = tid & 63;
  int bid = blockIdx.x;
  int r0 = bid * 16;
  int quad = lane >> 4, l15 = lane & 15;

  // ===== ph1: 4-way K-split GEMM =====
  {
    int kcb = 3 * wave;
    const float* arow = inp + (size_t)(r0 + l15) * DD + kcb * 64 + quad * 8;
    f32x4 pa0a = *(const f32x4*)(arow);
    f32x4 pa0b = *(const f32x4*)(arow + 4);
    f32x4 pa1a = *(const f32x4*)(arow + 32);
    f32x4 pa1b = *(const f32x4*)(arow + 36);

    f32x4 acc[2] = {};
#pragma unroll
    for (int kc = 0; kc < 3; ++kc) {
      Frag8 af0, af1;
      af0.u[0] = pk2(pa0a[0], pa0a[1]); af0.u[1] = pk2(pa0a[2], pa0a[3]);
      af0.u[2] = pk2(pa0b[0], pa0b[1]); af0.u[3] = pk2(pa0b[2], pa0b[3]);
      af1.u[0] = pk2(pa1a[0], pa1a[1]); af1.u[1] = pk2(pa1a[2], pa1a[3]);
      af1.u[2] = pk2(pa1b[0], pa1b[1]); af1.u[3] = pk2(pa1b[2], pa1b[3]);
      if (kc < 2) {
        const float* a2 = arow + (kc + 1) * 64;
        pa0a = *(const f32x4*)(a2);      pa0b = *(const f32x4*)(a2 + 4);
        pa1a = *(const f32x4*)(a2 + 32); pa1b = *(const f32x4*)(a2 + 36);
      }
#pragma unroll
      for (int ct = 0; ct < 2; ++ct) {
        const unsigned short* bp = Bw + (ct * 16 + l15) * DD + (kcb + kc) * 64 + quad * 8;
        s16x8 bf0 = *(const s16x8*)(bp);
        acc[ct] = __builtin_amdgcn_mfma_f32_16x16x32_bf16(af0.s, bf0, acc[ct], 0, 0, 0);
        s16x8 bf1 = *(const s16x8*)(bp + 32);
        acc[ct] = __builtin_amdgcn_mfma_f32_16x16x32_bf16(af1.s, bf1, acc[ct], 0, 0, 0);
      }
    }
#pragma unroll
    for (int ct = 0; ct < 2; ++ct)
#pragma unroll
      for (int r = 0; r < 4; ++r)
        ovl.accbuf[wave][quad * 4 + r][ct * 16 + l15] = acc[ct][r];
  }
  __syncthreads();

  // ===== ph3: all-thread reduce + epilogue -> osh + global outs =====
  {
#pragma unroll
    for (int u = 0; u < 2; ++u) {
      int v = tid * 2 + u;
      int lr = v >> 5, col = v & 31;
      if (col < NL) {
        float s = ovl.accbuf[0][lr][col] + ovl.accbuf[1][lr][col]
                + ovl.accbuf[2][lr][col] + ovl.accbuf[3][lr][col];
        s += sb[col];
        if (col == IDX_EOS && msk[r0 + lr] == 0.f) s += 20000.f;
        osh[lr * 32 + col] = s;
        outs[(size_t)(r0 + lr) * NL + col] = s;
      }
    }
  }
  __syncthreads();

  // batch-first block: save row 0 for the final p0
  if ((bid & 31) == 0 && tid < NL) out0[(bid >> 5) * NL + tid] = osh[tid];

  int l = lane & 31, h = lane >> 5;

  // ===== ph5: seg sub-product, 4 steps per wave (R4-verified code) =====
  {
    int s0 = ((bid & 31) == 0 && wave == 0) ? 1 : 0;  // t=0 is start dist
    float* ub = ovl.ubw[wave];
#pragma unroll
    for (int it = 0; it < 2; ++it) {
      int idx = lane + it * 64;
      int row = idx >> 5, col = idx & 31;
      float v = 0.f;
      if (col < NL) v = exp2f(LOG2E * osh[(4 * wave + row) * 32 + col]);
      ub[idx] = v;
    }

    Frag8 A1, A2, B1, B2;
#pragma unroll
    for (int m = 0; m < 4; ++m) {
      int k0 = 8 * h + 2 * m, k1 = k0 + 1;
      float a0 = (k0 < NL && l < NL) ? exp2f(LOG2E * trans[k0 * NL + l]) : 0.f;
      float a1 = (k1 < NL && l < NL) ? exp2f(LOG2E * trans[k1 * NL + l]) : 0.f;
      A1.u[m] = pk2(a0, a1);
      int k2 = 16 + k0, k3 = 16 + k1;
      float a2 = (k2 < NL && l < NL) ? exp2f(LOG2E * trans[k2 * NL + l]) : 0.f;
      float a3 = (k3 < NL && l < NL) ? exp2f(LOG2E * trans[k3 * NL + l]) : 0.f;
      A2.u[m] = pk2(a2, a3);
      B1.u[m] = ((k0 == l) ? 0x3f80u : 0u) | (((k1 == l) ? 0x3f80u : 0u) << 16);
      B2.u[m] = ((k2 == l) ? 0x3f80u : 0u) | (((k3 == l) ? 0x3f80u : 0u) << 16);
    }

    float E[16];
    for (int s = s0; s < 4; ++s) {
      const float* us = ub + s * 32 + 4 * h;
      f32x4 u0 = *(const f32x4*)(us);
      f32x4 u1 = *(const f32x4*)(us + 8);
      f32x4 u2 = *(const f32x4*)(us + 16);
      f32x4 u3 = *(const f32x4*)(us + 24);
      f32x16 D = {};
      D = __builtin_amdgcn_mfma_f32_32x32x16_bf16(A1.s, B1.s, D, 0, 0, 0);
      D = __builtin_amdgcn_mfma_f32_32x32x16_bf16(A2.s, B2.s, D, 0, 0, 0);
#pragma unroll
      for (int jj = 0; jj < 4; ++jj) {
        E[jj]      = D[jj]      * u0[jj];
        E[4 + jj]  = D[4 + jj]  * u1[jj];
        E[8 + jj]  = D[8 + jj]  * u2[jj];
        E[12 + jj] = D[12 + jj] * u3[jj];
      }
      if (s < 3) repack(E, h, B1, B2);
    }
    float S = 0.f;
    renorm16(E, S);
    unsigned short* mo = Ms[wave];
#pragma unroll
    for (int r = 0; r < 16; ++r) {
      int row = (r & 3) + 8 * (r >> 2) + 4 * h;
      mo[row * 32 + l] = bf16r(E[r]);
    }
    if (lane == 0) Ss[wave] = S;
  }
  __syncthreads();

  // ===== ph7: wave0 combine -> Mb/Sb; wave1 tgt partial =====
  if (wave == 0) {
    Frag8 A1, A2, B1, B2;
    load_B16(Ms[0], l, h, B1, B2);
    float Sx = Ss[0] + Ss[1] + Ss[2] + Ss[3];
    float E2[16];
#pragma unroll
    for (int i = 1; i < 4; ++i) {
      load_A16(Ms[i], l, h, A1, A2);
      f32x16 D = {};
      D = __builtin_amdgcn_mfma_f32_32x32x16_bf16(A1.s, B1.s, D, 0, 0, 0);
      D = __builtin_amdgcn_mfma_f32_32x32x16_bf16(A2.s, B2.s, D, 0, 0, 0);
#pragma unroll
      for (int r = 0; r < 16; ++r) E2[r] = D[r];
      if (i < 3) repack(E2, h, B1, B2);
    }
    renorm16(E2, Sx);
    unsigned short* qo = Mb + (size_t)bid * 1024;
#pragma unroll
    for (int r = 0; r < 16; ++r) {
      int row = (r & 3) + 8 * (r >> 2) + 4 * h;
      qo[row * 32 + l] = bf16r(E2[r]);
    }
    if (lane == 0) Sb[bid] = Sx;
  } else if (wave == 1 && lane < 16) {
    int r = r0 + lane;
    int tg = target[r];
    int prv = ((r & (TT - 1)) == 0) ? IDX_BOS : target[r - 1];
    float cc = trans[prv * NL + tg] + osh[lane * 32 + tg];
#pragma unroll
    for (int off = 8; off; off >>= 1) cc += __shfl_down(cc, off);
    if (lane == 0) ws_partial[bid] = cc;
  }
}

// ------------- K_B: pure energy stream (aligned reads AND aligned stores) ---
// 1024 blocks x 32 rows. trs[s][i] = trans[i+s] (4 shift-copies) makes every
// main-loop tr read an aligned ds_read_b128 (conflict-free); per-row shift
// off = (4 - r%4)&3 makes every f32x4 global store 16B-aligned (full-line,
// no L2 RMW). Head/tail (<=5 scalars/row) via idle slots. osh rows dup to 34.
__global__ __launch_bounds__(256, 8) void k_B(
    const float* __restrict__ outs, const float* __restrict__ trans,
    float* __restrict__ energy)
{
  __shared__ __align__(16) float trs[4][964];
  __shared__ __align__(16) float osh[32][34];
  int tid = threadIdx.x, wave = tid >> 6, lane = tid & 63;
  int r0 = blockIdx.x * 32;

#pragma unroll
  for (int s = 0; s < 4; ++s)
    for (int i = tid; i < 964; i += 256)
      trs[s][i] = (i + s < 961) ? trans[i + s] : 0.f;

  for (int idx = tid; idx < 32 * NL; idx += 256) {
    unsigned row = ((unsigned)idx * 67651u) >> 21;   // idx / 31 (exact)
    unsigned col = (unsigned)idx - row * 31u;
    float v = outs[(size_t)r0 * NL + idx];
    osh[row][col] = v;
    if (col < 3) osh[row][31 + col] = v;             // wrap-free j+3 reads
  }
  __syncthreads();

  for (int rr = 0; rr < 8; ++rr) {
    int r = wave * 8 + rr;
    int off = (4 - (r & 3)) & 3;                     // store alignment shift
    int S = (961 - off) >> 2;                        // full vec4 count
    const float* tcopy = trs[off];
    const float* orow = osh[r];
    float* drow = energy + (size_t)(r0 + r) * 961;
#pragma unroll
    for (int it = 0; it < 4; ++it) {
      int slot = lane + (it << 6);
      if (slot < S) {
        int e = off + (slot << 2);
        f32x4 t4 = *(const f32x4*)(tcopy + (slot << 2));  // aligned, conflict-free
        unsigned j = (unsigned)e - 31u * (((unsigned)e * 67651u) >> 21); // e%31
        f32x4 val;
#pragma unroll
        for (int k = 0; k < 4; ++k) val[k] = t4[k] + orow[j + k];
        *(f32x4*)(drow + e) = val;                   // 16B-aligned full-line store
      } else if (it == 3) {
        int t = slot - S;
        int total = 961 - (S << 2);                  // head(off) + tail
        if (t < total) {
          int e = (t < off) ? t : ((S << 2) + t);    // head: 0..off-1; tail: off+4S..960
          unsigned j = (unsigned)e - 31u * (((unsigned)e * 67651u) >> 21);
          drow[e] = trs[0][e] + orow[j];
        }
      }
    }
  }
}

// ------------- K2: per-batch depth-5 tree over 32 segment matrices + loss ---
__global__ __launch_bounds__(256) void k_tree(
    const float* __restrict__ trans, const unsigned short* __restrict__ Mb,
    const float* __restrict__ Sb, const float* __restrict__ ws_partial,
    const float* __restrict__ out0, float* __restrict__ loss)
{
  __shared__ __align__(16) unsigned short T[32][1024];
  __shared__ float Ts[32];
  __shared__ float wsh[32];
  int tid = threadIdx.x, wave = tid >> 6, lane = tid & 63;
  int l = lane & 31, h = lane >> 5;
  int b = blockIdx.x;

  const f32x4* src = (const f32x4*)(Mb + (size_t)b * 32 * 1024);
  f32x4* dstT = (f32x4*)T;
#pragma unroll
  for (int i = 0; i < 16; ++i) dstT[tid + i * 256] = src[tid + i * 256];
  if (tid < 32) {
    Ts[tid] = Sb[b * 32 + tid];
    wsh[tid] = ws_partial[b * 32 + tid];
  }
  __syncthreads();

  unsigned short* T0 = T[0];
#pragma unroll
  for (int i = 0; i < 4; ++i) { int j = wave + 4 * i; tree_node(T0, Ts, 2 * j + 1, 2 * j, l, h); }
  __syncthreads();
#pragma unroll
  for (int i = 0; i < 2; ++i) { int j = wave + 4 * i; tree_node(T0, Ts, 4 * j + 2, 4 * j, l, h); }
  __syncthreads();
  { int j = wave; tree_node(T0, Ts, 8 * j + 4, 8 * j, l, h); }
  __syncthreads();
  if (wave < 2) { int j = wave; tree_node(T0, Ts, 16 * j + 8, 16 * j, l, h); }
  __syncthreads();

  if (wave == 0) {
    Frag8 A1, A2, B1, B2;
    load_A16(T0 + 16 * 1024, l, h, A1, A2);
    load_B16(T0, l, h, B1, B2);
    f32x16 D = {};
    D = __builtin_amdgcn_mfma_f32_32x32x16_bf16(A1.s, B1.s, D, 0, 0, 0);
    D = __builtin_amdgcn_mfma_f32_32x32x16_bf16(A2.s, B2.s, D, 0, 0, 0);
    float E[16];
#pragma unroll
    for (int r = 0; r < 16; ++r) E[r] = D[r];
    float S = Ts[0] + Ts[16];

    float p0 = (l < NL) ? exp2f(LOG2E * (trans[IDX_BOS * NL + l] + out0[b * NL + l])) : 0.f;
    float sum_h = 0.f;
#pragma unroll
    for (int r = 0; r < 16; ++r) {
      float s = bfly_sum32(E[r] * p0);
      int row = (r & 3) + 8 * (r >> 2) + 4 * h;
      float We = (row < NL) ? exp2f(LOG2E * trans[row * NL + IDX_EOS]) : 0.f;
      sum_h += s * We;
    }
    float tot = sum_h + __shfl_xor(sum_h, 32);
    if (lane == 0) {
      float wst = 0.f;
#pragma unroll
      for (int i = 0; i < 32; ++i) wst += wsh[i];
      loss[b] = LN2F * (S + log2f(tot)) - wst;
    }
  }
}

extern "C" void kernel_launch(void* const* d_in, const int* in_sizes, int n_in,
                              void* d_out, int out_size, void* d_ws, size_t ws_size,
                              hipStream_t stream) {
  const float* inp   = (const float*)d_in[0];   // (64,512,768) f32
  const int*   tgt   = (const int*)d_in[1];     // (64,512) int
  const float* msk   = (const float*)d_in[2];   // (64,512) f32
  const float* sw    = (const float*)d_in[3];   // (31,768) f32
  const float* sb    = (const float*)d_in[4];   // (31,) f32
  const float* trans = (const float*)d_in[5];   // (31,31) f32

  float* out    = (float*)d_out;
  float* loss   = out;
  float* energy = out + BB;

  // d_ws layout (~8.2 MB used)
  float* ws_partial = (float*)d_ws;                    // 2048
  float* Sb   = ws_partial + 2048;                     // 2048
  float* out0 = Sb + 2048;                             // 64*31 -> pad 2048
  float* outs = out0 + 2048;                           // RTOT*31 f32 (4.06 MB)
  unsigned short* Mb = (unsigned short*)(outs + (size_t)RTOT * NL); // 2048*1024 bf16
  unsigned short* Bw = Mb + (size_t)2048 * 1024;       // 32*768 bf16

  k_prep<<<8, 256, 0, stream>>>(sw, Bw);
  k_A<<<RTOT / 16, 256, 0, stream>>>(inp, Bw, sb, msk, trans, tgt,
                                     outs, ws_partial, Mb, Sb, out0);
  k_B<<<1024, 256, 0, stream>>>(outs, trans, energy);
  k_tree<<<BB, 256, 0, stream>>>(trans, Mb, Sb, ws_partial, out0, loss);
}

// Round 8
// 269.116 us; speedup vs baseline: 1.1952x; 1.1952x over previous
//
#include <hip/hip_runtime.h>

typedef float f32x4  __attribute__((ext_vector_type(4)));
typedef float f32x16 __attribute__((ext_vector_type(16)));
typedef short s16x8  __attribute__((ext_vector_type(8)));

constexpr int NL  = 31;
constexpr int BB  = 64;
constexpr int TT  = 512;
constexpr int DD  = 768;
constexpr int RTOT = BB * TT;
constexpr int IDX_EOS = 29;
constexpr int IDX_BOS = 30;
constexpr float LOG2E = 1.4426950408889634f;
constexpr float LN2F  = 0.6931471805599453f;

union Frag8 { unsigned u[4]; s16x8 s; };

__device__ inline unsigned pk2(float a, float b) {
  unsigned ua = __float_as_uint(a), ub = __float_as_uint(b);
  ua = (ua + 0x7fffu + ((ua >> 16) & 1u)) >> 16;   // RNE f32->bf16
  ub = (ub + 0x7fffu + ((ub >> 16) & 1u)) >> 16;
  return ua | (ub << 16);
}
__device__ inline unsigned short bf16r(float a) {
  unsigned ua = __float_as_uint(a);
  return (unsigned short)((ua + 0x7fffu + ((ua >> 16) & 1u)) >> 16);
}

// async global->LDS, 16B per lane; LDS dest = wave-uniform base + lane*16
__device__ inline void gload16(const float* g, void* l) {
  __builtin_amdgcn_global_load_lds(
      (__attribute__((address_space(1))) void*)(void*)g,
      (__attribute__((address_space(3))) void*)l, 16, 0, 0);
}

__device__ inline float bfly_max32(float v) {
#define STEPM(K) { float o = __int_as_float(__builtin_amdgcn_ds_swizzle(__float_as_int(v), ((K) << 10) | 0x1f)); v = fmaxf(v, o); }
  STEPM(1) STEPM(2) STEPM(4) STEPM(8) STEPM(16)
#undef STEPM
  return v;
}
__device__ inline float bfly_sum32(float v) {
#define STEPS(K) { float o = __int_as_float(__builtin_amdgcn_ds_swizzle(__float_as_int(v), ((K) << 10) | 0x1f)); v = v + o; }
  STEPS(1) STEPS(2) STEPS(4) STEPS(8) STEPS(16)
#undef STEPS
  return v;
}

// D(C-layout, f32[16]) -> B-frag(bf16) half-swap repack [R2-verified]
__device__ inline void repack(const float E[16], int h, Frag8& B1, Frag8& B2) {
  unsigned o1a = pk2(E[4 * h], E[4 * h + 1]), o1b = pk2(E[4 * h + 2], E[4 * h + 3]);
  unsigned o2a = pk2(E[8 + 4 * h], E[8 + 4 * h + 1]), o2b = pk2(E[8 + 4 * h + 2], E[8 + 4 * h + 3]);
  int hb = 4 * (1 - h);
  unsigned s1a = pk2(E[hb], E[hb + 1]),         s1b = pk2(E[hb + 2], E[hb + 3]);
  unsigned s2a = pk2(E[8 + hb], E[8 + hb + 1]), s2b = pk2(E[8 + hb + 2], E[8 + hb + 3]);
  unsigned r1a = __shfl_xor((int)s1a, 32), r1b = __shfl_xor((int)s1b, 32);
  unsigned r2a = __shfl_xor((int)s2a, 32), r2b = __shfl_xor((int)s2b, 32);
  if (h == 0) {
    B1.u[0] = o1a; B1.u[1] = o1b; B1.u[2] = r1a; B1.u[3] = r1b;
    B2.u[0] = o2a; B2.u[1] = o2b; B2.u[2] = r2a; B2.u[3] = r2b;
  } else {
    B1.u[0] = r1a; B1.u[1] = r1b; B1.u[2] = o1a; B1.u[3] = o1b;
    B2.u[0] = r2a; B2.u[1] = r2b; B2.u[2] = o2a; B2.u[3] = o2b;
  }
}

__device__ inline void renorm16(float E[16], float& Sacc) {
  float m = E[0];
#pragma unroll
  for (int r = 1; r < 16; ++r) m = fmaxf(m, E[r]);
  m = bfly_max32(m);
  m = fmaxf(m, __shfl_xor(m, 32));
  float lg = truncf(log2f(m));
  Sacc += lg;
  float sc = exp2f(-lg);
#pragma unroll
  for (int r = 0; r < 16; ++r) E[r] *= sc;
}

// bf16 row-major 32x32 matrix -> A-frags (A[m][k], m = lane&31)
__device__ inline void load_A16(const unsigned short* M, int l, int h, Frag8& A1, Frag8& A2) {
  A1.s = *(const s16x8*)(M + l * 32 + 8 * h);
  A2.s = *(const s16x8*)(M + l * 32 + 16 + 8 * h);
}
// bf16 row-major 32x32 matrix -> B-frags (B[k][n], n = lane&31)
__device__ inline void load_B16(const unsigned short* M, int l, int h, Frag8& B1, Frag8& B2) {
#pragma unroll
  for (int m = 0; m < 4; ++m) {
    int k = 8 * h + 2 * m;
    unsigned lo0 = M[k * 32 + l],        hi0 = M[(k + 1) * 32 + l];
    unsigned lo1 = M[(k + 16) * 32 + l], hi1 = M[(k + 17) * 32 + l];
    B1.u[m] = lo0 | (hi0 << 16);
    B2.u[m] = lo1 | (hi1 << 16);
  }
}

// LDS tree node: T[jb] <- T[ja] * T[jb] (ja LATER, jb EARLIER). Renorm only
// when RN (S + log2(tot) absorbs scale; renorm is range control only).
template<bool RN>
__device__ inline void tree_node(unsigned short* Tb, float* Ts, int ja, int jb, int l, int h) {
  Frag8 A1, A2, B1, B2;
  load_A16(Tb + ja * 1024, l, h, A1, A2);
  load_B16(Tb + jb * 1024, l, h, B1, B2);
  f32x16 D = {};
  D = __builtin_amdgcn_mfma_f32_32x32x16_bf16(A1.s, B1.s, D, 0, 0, 0);
  D = __builtin_amdgcn_mfma_f32_32x32x16_bf16(A2.s, B2.s, D, 0, 0, 0);
  float E[16];
#pragma unroll
  for (int r = 0; r < 16; ++r) E[r] = D[r];
  float S = Ts[ja] + Ts[jb];
  if (RN) renorm16(E, S);
#pragma unroll
  for (int r = 0; r < 16; ++r) {
    int row = (r & 3) + 8 * (r >> 2) + 4 * h;
    Tb[jb * 1024 + row * 32 + l] = bf16r(E[r]);
  }
  if (l == 0 && h == 0) Ts[jb] = S;
}

// row-based energy stream (R7 k_B pattern: aligned b128 tr reads via shifted
// copies + 16B-aligned full-line stores; osh rows dup'd to 34 cols)
__device__ inline void energy_rows(float* dst0, const float trs[4][964],
                                   const float osh[16][34],
                                   int rbeg, int rend, int lane) {
  for (int r = rbeg; r < rend; ++r) {
    int off = (4 - (r & 3)) & 3;
    int S = (961 - off) >> 2;
    const float* tcopy = trs[off];
    const float* orow = osh[r];
    float* drow = dst0 + (size_t)r * 961;
#pragma unroll
    for (int it = 0; it < 4; ++it) {
      int slot = lane + (it << 6);
      if (slot < S) {
        int e = off + (slot << 2);
        f32x4 t4 = *(const f32x4*)(tcopy + (slot << 2));
        unsigned j = (unsigned)e - 31u * (((unsigned)e * 67651u) >> 21);
        f32x4 val;
#pragma unroll
        for (int k = 0; k < 4; ++k) val[k] = t4[k] + orow[j + k];
        *(f32x4*)(drow + e) = val;
      } else if (it == 3) {
        int t = slot - S;
        int total = 961 - (S << 2);
        if (t < total) {
          int e = (t < off) ? t : ((S << 2) + t);
          unsigned j = (unsigned)e - 31u * (((unsigned)e * 67651u) >> 21);
          drow[e] = trs[0][e] + orow[j];
        }
      }
    }
  }
}

// ------------- K0: state_w -> bf16 padded ----------------------------------
__global__ void k_prep(const float* __restrict__ sw, unsigned short* __restrict__ Bw) {
  for (int i = blockIdx.x * 256 + threadIdx.x; i < 32 * DD; i += 8 * 256)
    Bw[i] = (i < NL * DD) ? bf16r(sw[i]) : (unsigned short)0;
}

// ------------- K1: everything (GEMM + energy + tgt + seg) -------------------
// 2048 blocks x 16 rows, 3 blocks/CU (48 KB tile). Phases:
//  S : async-stage 48 KB f32 inp tile via global_load_lds (12 issues/wave,
//      XOR-preswizzled global source, linear LDS dest)  -> deep read queue
//  G : 4-way K-split GEMM from LDS (swizzled ds_read_b128, acc in regs)
//  R : accbuf reduce + epilogue -> osh; co-load trs (tile dead, LDS reused)
//  P5: 4-step seg sub-product per wave -> Ms/Ss
//  P7: wave0 combine -> Mb/Sb + 1 energy row; wave1 tgt; waves1-3 5 rows each
__global__ __launch_bounds__(256, 3) void k_fused(
    const float* __restrict__ inp, const unsigned short* __restrict__ Bw,
    const float* __restrict__ sb, const float* __restrict__ msk,
    const float* __restrict__ trans, const int* __restrict__ target,
    float* __restrict__ energy, float* __restrict__ ws_partial,
    unsigned short* __restrict__ Mb, float* __restrict__ Sb,
    float* __restrict__ out0)
{
  __shared__ __align__(1024) union SM {
    float tileF[16][768];            // 48 KB f32 inp tile (XOR-swizzled 16B units)
    struct {
      float accbuf[4][16][33];       // 8.4 KB
      float trs[4][964];             // 15.4 KB shifted trans copies
      float osh[16][34];             // 2.2 KB (+3 dup cols)
      float ubw[4][128];             // 2 KB
      unsigned short Ms[4][1024];    // 8 KB
      float Ss[4];
    } p;
  } sm;

  int tid = threadIdx.x, wave = tid >> 6, lane = tid & 63;
  int bid = blockIdx.x;
  int r0 = bid * 16;
  int quad = lane >> 4, l15 = lane & 15;
  int l = lane & 31, h = lane >> 5;

  // ===== S: async stage; wave w stages rows 4w..4w+3 (3x 1KB issues/row) ====
  {
#pragma unroll
    for (int rr = 0; rr < 4; ++rr) {
      int r = wave * 4 + rr;
      int s = r & 7;
      const float* gr = inp + (size_t)(r0 + r) * DD;
      float* lrow = &sm.tileF[r][0];
#pragma unroll
      for (int j = 0; j < 3; ++j)
        gload16(gr + (j * 64 + (lane ^ s)) * 4, lrow + j * 256);
    }
  }
  __syncthreads();   // drains vmcnt -> tile complete

  // ===== G: 4-way K-split GEMM from LDS (acc stays in registers) ===========
  f32x4 acc[2] = {};
  {
    int sA = l15 & 7;
    const float* tf = &sm.tileF[l15][0];
    int kcb = 3 * wave;
#pragma unroll
    for (int kc = 0; kc < 3; ++kc) {
      int u0 = (kcb + kc) * 16 + quad * 2;
      f32x4 a0 = *(const f32x4*)(tf + ((u0)     ^ sA) * 4);
      f32x4 a1 = *(const f32x4*)(tf + ((u0 + 1) ^ sA) * 4);
      f32x4 a2 = *(const f32x4*)(tf + ((u0 + 8) ^ sA) * 4);
      f32x4 a3 = *(const f32x4*)(tf + ((u0 + 9) ^ sA) * 4);
      Frag8 af0, af1;
      af0.u[0] = pk2(a0[0], a0[1]); af0.u[1] = pk2(a0[2], a0[3]);
      af0.u[2] = pk2(a1[0], a1[1]); af0.u[3] = pk2(a1[2], a1[3]);
      af1.u[0] = pk2(a2[0], a2[1]); af1.u[1] = pk2(a2[2], a2[3]);
      af1.u[2] = pk2(a3[0], a3[1]); af1.u[3] = pk2(a3[2], a3[3]);
#pragma unroll
      for (int ct = 0; ct < 2; ++ct) {
        const unsigned short* bp = Bw + (ct * 16 + l15) * DD + (kcb + kc) * 64 + quad * 8;
        s16x8 bf0 = *(const s16x8*)(bp);
        acc[ct] = __builtin_amdgcn_mfma_f32_16x16x32_bf16(af0.s, bf0, acc[ct], 0, 0, 0);
        s16x8 bf1 = *(const s16x8*)(bp + 32);
        acc[ct] = __builtin_amdgcn_mfma_f32_16x16x32_bf16(af1.s, bf1, acc[ct], 0, 0, 0);
      }
    }
  }
  __syncthreads();   // tile dead everywhere -> LDS reusable

  // ===== write acc partials + co-load shifted trans copies =================
  {
#pragma unroll
    for (int ct = 0; ct < 2; ++ct)
#pragma unroll
      for (int r = 0; r < 4; ++r)
        sm.p.accbuf[wave][quad * 4 + r][ct * 16 + l15] = acc[ct][r];
#pragma unroll
    for (int s = 0; s < 4; ++s)
      for (int i = tid; i < 964; i += 256)
        sm.p.trs[s][i] = (i + s < 961) ? trans[i + s] : 0.f;
  }
  __syncthreads();

  // ===== R: reduce + epilogue -> osh ======================================
  {
#pragma unroll
    for (int u = 0; u < 2; ++u) {
      int v = tid * 2 + u;
      int lr = v >> 5, col = v & 31;
      if (col < NL) {
        float s = sm.p.accbuf[0][lr][col] + sm.p.accbuf[1][lr][col]
                + sm.p.accbuf[2][lr][col] + sm.p.accbuf[3][lr][col];
        s += sb[col];
        if (col == IDX_EOS && msk[r0 + lr] == 0.f) s += 20000.f;
        sm.p.osh[lr][col] = s;
        if (col < 3) sm.p.osh[lr][31 + col] = s;   // wrap-free j+3 energy reads
      }
    }
  }
  __syncthreads();

  // batch-first block: save row 0 for the final p0
  if ((bid & 31) == 0 && tid < NL) out0[(bid >> 5) * NL + tid] = sm.p.osh[0][tid];

  // ===== P5: seg sub-product, 4 steps per wave (R4/R7-verified) ============
  {
    int s0 = ((bid & 31) == 0 && wave == 0) ? 1 : 0;  // t=0 is start dist
    float* ub = sm.p.ubw[wave];
#pragma unroll
    for (int it = 0; it < 2; ++it) {
      int idx = lane + it * 64;
      int row = idx >> 5, col = idx & 31;
      float v = 0.f;
      if (col < NL) v = exp2f(LOG2E * sm.p.osh[4 * wave + row][col]);
      ub[idx] = v;
    }

    Frag8 A1, A2, B1, B2;
#pragma unroll
    for (int m = 0; m < 4; ++m) {
      int k0 = 8 * h + 2 * m, k1 = k0 + 1;
      float a0 = (k0 < NL && l < NL) ? exp2f(LOG2E * sm.p.trs[0][k0 * NL + l]) : 0.f;
      float a1 = (k1 < NL && l < NL) ? exp2f(LOG2E * sm.p.trs[0][k1 * NL + l]) : 0.f;
      A1.u[m] = pk2(a0, a1);
      int k2 = 16 + k0, k3 = 16 + k1;
      float a2 = (k2 < NL && l < NL) ? exp2f(LOG2E * sm.p.trs[0][k2 * NL + l]) : 0.f;
      float a3 = (k3 < NL && l < NL) ? exp2f(LOG2E * sm.p.trs[0][k3 * NL + l]) : 0.f;
      A2.u[m] = pk2(a2, a3);
      B1.u[m] = ((k0 == l) ? 0x3f80u : 0u) | (((k1 == l) ? 0x3f80u : 0u) << 16);
      B2.u[m] = ((k2 == l) ? 0x3f80u : 0u) | (((k3 == l) ? 0x3f80u : 0u) << 16);
    }

    float E[16];
    for (int s = s0; s < 4; ++s) {
      const float* us = ub + s * 32 + 4 * h;
      f32x4 u0 = *(const f32x4*)(us);
      f32x4 u1 = *(const f32x4*)(us + 8);
      f32x4 u2 = *(const f32x4*)(us + 16);
      f32x4 u3 = *(const f32x4*)(us + 24);
      f32x16 D = {};
      D = __builtin_amdgcn_mfma_f32_32x32x16_bf16(A1.s, B1.s, D, 0, 0, 0);
      D = __builtin_amdgcn_mfma_f32_32x32x16_bf16(A2.s, B2.s, D, 0, 0, 0);
#pragma unroll
      for (int jj = 0; jj < 4; ++jj) {
        E[jj]      = D[jj]      * u0[jj];
        E[4 + jj]  = D[4 + jj]  * u1[jj];
        E[8 + jj]  = D[8 + jj]  * u2[jj];
        E[12 + jj] = D[12 + jj] * u3[jj];
      }
      if (s < 3) repack(E, h, B1, B2);
    }
    float S = 0.f;
    renorm16(E, S);
    unsigned short* mo = sm.p.Ms[wave];
#pragma unroll
    for (int r = 0; r < 16; ++r) {
      int row = (r & 3) + 8 * (r >> 2) + 4 * h;
      mo[row * 32 + l] = bf16r(E[r]);
    }
    if (lane == 0) sm.p.Ss[wave] = S;
  }
  __syncthreads();

  // ===== P7: wave0 combine + row 15; wave1 tgt; waves1-3 energy rows ========
  float* dst0 = energy + (size_t)r0 * 961;
  if (wave == 0) {
    Frag8 A1, A2, B1, B2;
    load_B16(sm.p.Ms[0], l, h, B1, B2);
    float Sx = sm.p.Ss[0] + sm.p.Ss[1] + sm.p.Ss[2] + sm.p.Ss[3];
    float E2[16];
#pragma unroll
    for (int i = 1; i < 4; ++i) {
      load_A16(sm.p.Ms[i], l, h, A1, A2);
      f32x16 D = {};
      D = __builtin_amdgcn_mfma_f32_32x32x16_bf16(A1.s, B1.s, D, 0, 0, 0);
      D = __builtin_amdgcn_mfma_f32_32x32x16_bf16(A2.s, B2.s, D, 0, 0, 0);
#pragma unroll
      for (int r = 0; r < 16; ++r) E2[r] = D[r];
      if (i < 3) repack(E2, h, B1, B2);
    }
    renorm16(E2, Sx);
    unsigned short* qo = Mb + (size_t)bid * 1024;
#pragma unroll
    for (int r = 0; r < 16; ++r) {
      int row = (r & 3) + 8 * (r >> 2) + 4 * h;
      qo[row * 32 + l] = bf16r(E2[r]);
    }
    if (lane == 0) Sb[bid] = Sx;
    energy_rows(dst0, sm.p.trs, sm.p.osh, 15, 16, lane);
  } else {
    if (wave == 1 && lane < 16) {
      int r = r0 + lane;
      int tg = target[r];
      int prv = ((r & (TT - 1)) == 0) ? IDX_BOS : target[r - 1];
      float cc = sm.p.trs[0][prv * NL + tg] + sm.p.osh[lane][tg];
#pragma unroll
      for (int off = 8; off; off >>= 1) cc += __shfl_down(cc, off);
      if (lane == 0) ws_partial[bid] = cc;
    }
    int rb = 5 * (wave - 1);
    energy_rows(dst0, sm.p.trs, sm.p.osh, rb, rb + 5, lane);
  }
}

// ------------- K2: per-batch depth-5 tree (renorm only at L3) + loss --------
__global__ __launch_bounds__(256) void k_tree(
    const float* __restrict__ trans, const unsigned short* __restrict__ Mb,
    const float* __restrict__ Sb, const float* __restrict__ ws_partial,
    const float* __restrict__ out0, float* __restrict__ loss)
{
  __shared__ __align__(16) unsigned short T[32][1024];
  __shared__ float Ts[32];
  __shared__ float wsh[32];
  int tid = threadIdx.x, wave = tid >> 6, lane = tid & 63;
  int l = lane & 31, h = lane >> 5;
  int b = blockIdx.x;

  const f32x4* src = (const f32x4*)(Mb + (size_t)b * 32 * 1024);
  f32x4* dstT = (f32x4*)T;
#pragma unroll
  for (int i = 0; i < 16; ++i) dstT[tid + i * 256] = src[tid + i * 256];
  if (tid < 32) {
    Ts[tid] = Sb[b * 32 + tid];
    wsh[tid] = ws_partial[b * 32 + tid];
  }
  __syncthreads();

  unsigned short* T0 = T[0];
  // L1 (32->16), no renorm (max <= 2^7)
#pragma unroll
  for (int i = 0; i < 4; ++i) { int j = wave + 4 * i; tree_node<false>(T0, Ts, 2 * j + 1, 2 * j, l, h); }
  __syncthreads();
  // L2 (16->8), no renorm (max <= 2^19)
#pragma unroll
  for (int i = 0; i < 2; ++i) { int j = wave + 4 * i; tree_node<false>(T0, Ts, 4 * j + 2, 4 * j, l, h); }
  __syncthreads();
  // L3 (8->4), RENORM (max <= 2^43 -> back to [1,2))
  { int j = wave; tree_node<true>(T0, Ts, 8 * j + 4, 8 * j, l, h); }
  __syncthreads();
  // L4 (4->2), no renorm
  if (wave < 2) { int j = wave; tree_node<false>(T0, Ts, 16 * j + 8, 16 * j, l, h); }
  __syncthreads();

  // L5 + finalize (wave 0): full = T[16] * T[0]
  if (wave == 0) {
    Frag8 A1, A2, B1, B2;
    load_A16(T0 + 16 * 1024, l, h, A1, A2);
    load_B16(T0, l, h, B1, B2);
    f32x16 D = {};
    D = __builtin_amdgcn_mfma_f32_32x32x16_bf16(A1.s, B1.s, D, 0, 0, 0);
    D = __builtin_amdgcn_mfma_f32_32x32x16_bf16(A2.s, B2.s, D, 0, 0, 0);
    float E[16];
#pragma unroll
    for (int r = 0; r < 16; ++r) E[r] = D[r];
    float S = Ts[0] + Ts[16];

    float p0 = (l < NL) ? exp2f(LOG2E * (trans[IDX_BOS * NL + l] + out0[b * NL + l])) : 0.f;
    float sum_h = 0.f;
#pragma unroll
    for (int r = 0; r < 16; ++r) {
      float s = bfly_sum32(E[r] * p0);
      int row = (r & 3) + 8 * (r >> 2) + 4 * h;
      float We = (row < NL) ? exp2f(LOG2E * trans[row * NL + IDX_EOS]) : 0.f;
      sum_h += s * We;
    }
    float tot = sum_h + __shfl_xor(sum_h, 32);
    if (lane == 0) {
      float wst = 0.f;
#pragma unroll
      for (int i = 0; i < 32; ++i) wst += wsh[i];
      loss[b] = LN2F * (S + log2f(tot)) - wst;
    }
  }
}

extern "C" void kernel_launch(void* const* d_in, const int* in_sizes, int n_in,
                              void* d_out, int out_size, void* d_ws, size_t ws_size,
                              hipStream_t stream) {
  const float* inp   = (const float*)d_in[0];   // (64,512,768) f32
  const int*   tgt   = (const int*)d_in[1];     // (64,512) int
  const float* msk   = (const float*)d_in[2];   // (64,512) f32
  const float* sw    = (const float*)d_in[3];   // (31,768) f32
  const float* sb    = (const float*)d_in[4];   // (31,) f32
  const float* trans = (const float*)d_in[5];   // (31,31) f32

  float* out    = (float*)d_out;
  float* loss   = out;
  float* energy = out + BB;

  // d_ws layout (~4.2 MB used)
  float* ws_partial = (float*)d_ws;                    // 2048
  float* Sb   = ws_partial + 2048;                     // 2048
  float* out0 = Sb + 2048;                             // 64*31 -> pad 2048
  unsigned short* Mb = (unsigned short*)(out0 + 2048); // 2048*1024 bf16
  unsigned short* Bw = Mb + (size_t)2048 * 1024;       // 32*768 bf16

  k_prep<<<8, 256, 0, stream>>>(sw, Bw);
  k_fused<<<RTOT / 16, 256, 0, stream>>>(inp, Bw, sb, msk, trans, tgt,
                                         energy, ws_partial, Mb, Sb, out0);
  k_tree<<<BB, 256, 0, stream>>>(trans, Mb, Sb, ws_partial, out0, loss);
}